// Round 6
// baseline (369.113 us; speedup 1.0000x reference)
//
#include <hip/hip_runtime.h>
#include <hip/hip_bf16.h>

// Shapes (fixed by the reference)
#define QN 64
#define SQ 32
#define CN 256
#define SC 256
#define HD 768
#define DD 128

typedef __attribute__((ext_vector_type(8))) short short8;   // 8 bf16 = 4 VGPR
typedef __attribute__((ext_vector_type(4))) float f32x4;    // MFMA acc

// ---- bf16 pack helpers (RNE) ----
static __device__ __forceinline__ unsigned short f2bf(float x) {
  unsigned u = __float_as_uint(x);
  unsigned r = 0x7FFFu + ((u >> 16) & 1u);
  return (unsigned short)((u + r) >> 16);
}
static __device__ __forceinline__ unsigned pack2(float a, float b) {
  return (unsigned)f2bf(a) | ((unsigned)f2bf(b) << 16);
}

// ---- async global->LDS, 16B/lane; LDS dest = wave-uniform base + lane*16 ----
typedef const __attribute__((address_space(1))) unsigned int* as1_u32p;
typedef __attribute__((address_space(3))) unsigned int* as3_u32p;
static __device__ __forceinline__ void gl_lds16(const void* g, void* l) {
  __builtin_amdgcn_global_load_lds((as1_u32p)g, (as3_u32p)l, 16, 0, 0);
}

// ---------------------------------------------------------------------------
// Prep (fused):
//  blocks [0,128):  WtS[d][k] = bf16(W[k][d])  (plain transpose, no swizzle)
//  blocks [128,448): pooled l2norm rows (64 q + 256 c); q rows also zero
//                   qcolP pad row 31.
// ---------------------------------------------------------------------------
__global__ __launch_bounds__(256) void prep_kernel(
    const float* __restrict__ W,
    const float* __restrict__ qh, const int* __restrict__ qm,
    const float* __restrict__ ch, const int* __restrict__ cm,
    unsigned short* __restrict__ WtS,
    float* __restrict__ outq, float* __restrict__ outc,
    unsigned short* __restrict__ qcolP) {
  __shared__ float red[4];
  int bid = blockIdx.x, tid = threadIdx.x;

  if (bid < DD) {  // W transpose-convert
    int d = bid;
    for (int k = tid; k < HD; k += 256)
      WtS[(size_t)d * HD + k] = f2bf(W[(size_t)k * DD + d]);
    return;
  }

  int row = bid - DD;
  const float* src;
  float* dst;
  float m;
  if (row < QN) {
    src = qh + (size_t)row * SQ * HD;
    m = (float)qm[row * SQ];
    dst = outq + (size_t)row * HD;
  } else {
    int b = row - QN;
    src = ch + (size_t)b * SC * HD;
    m = (float)cm[b * SC];
    dst = outc + (size_t)b * HD;
  }
  float ss = 0.f;
  for (int k = tid; k < HD; k += 256) {
    float v = src[k] * m;
    ss += v * v;
  }
  int lane = tid & 63, wv = tid >> 6;
  for (int off = 32; off; off >>= 1) ss += __shfl_xor(ss, off);
  if (lane == 0) red[wv] = ss;
  __syncthreads();
  float tot = red[0] + red[1] + red[2] + red[3];
  float inv = 1.f / fmaxf(sqrtf(tot), 1e-12f);
  for (int k = tid; k < HD; k += 256) dst[k] = src[k] * m * inv;
  if (row < QN && tid < 64)
    ((unsigned*)(qcolP + ((size_t)row * 32 + 31) * DD))[tid] = 0u;
}

// ---------------------------------------------------------------------------
// Projection GEMM (MFMA, barrier-free): col = l2norm(m*(h@W) + b)
//  1-wave blocks (64 thr). Blocks [0,2040): c tokens; [2040,2102): q tokens.
//  Each wave: 32 tokens x 128 d x K=768, 24 k-windows of 32.
//  A-frags: global f32 -> VGPR (2 float4/lane; 16 rows x 128 B, coalesced).
//  W-frags: global bf16 16 B/lane from WtS[d][k] (L2-resident, 192 KB).
//  NO __syncthreads in the K-loop -> compiler pipelines with vmcnt(N).
//  Epilogue through wave-private LDS; mask in epilogue (exact identity).
//  ccol stored chunk-swizzled: pos = (kc&8)|((kc&7)^(t&7)) for sim's reads.
// ---------------------------------------------------------------------------
__global__ __launch_bounds__(64, 2) void proj_kernel(
    const float* __restrict__ q_hidden, const float* __restrict__ c_hidden,
    const int* __restrict__ q_mask, const int* __restrict__ c_mask,
    const unsigned short* __restrict__ WtS, const float* __restrict__ bias,
    unsigned short* __restrict__ qcol, unsigned short* __restrict__ ccol) {
  __shared__ float cep[32 * 132];  // 16.9 KB, wave-private
  int bx = blockIdx.x;
  int isQ = (bx >= 2040) ? 1 : 0;
  int tokbase = (isQ ? (bx - 2040) : bx) * 32;
  int lane = threadIdx.x & 63;
  int lm = lane & 15, lq = lane >> 4;

  // A row pointers (token = tokbase + mt*16 + lm), k-offset lq*8
  const float* arow[2];
#pragma unroll
  for (int mt = 0; mt < 2; ++mt) {
    int g = tokbase + mt * 16 + lm;
    if (isQ) {
      int qq = g / 31, t = g - qq * 31;
      arow[mt] = q_hidden + ((size_t)qq * SQ + t + 1) * HD + lq * 8;
    } else {
      int cb = g / 255, t = g - cb * 255;
      arow[mt] = c_hidden + ((size_t)cb * SC + t + 1) * HD + lq * 8;
    }
  }
  const unsigned short* wrow = WtS + (size_t)lm * HD + lq * 8;

  f32x4 acc[2][8];
#pragma unroll
  for (int i = 0; i < 2; ++i)
#pragma unroll
    for (int j = 0; j < 8; ++j) acc[i][j] = (f32x4){0.f, 0.f, 0.f, 0.f};

  // 1-deep prefetch pipeline over 24 k-windows (no barriers anywhere)
  float4 pa[2][2];
  short8 pw[8];
#pragma unroll
  for (int mt = 0; mt < 2; ++mt) {
    pa[mt][0] = *(const float4*)(arow[mt]);
    pa[mt][1] = *(const float4*)(arow[mt] + 4);
  }
#pragma unroll
  for (int nt = 0; nt < 8; ++nt)
    pw[nt] = *(const short8*)(wrow + (size_t)nt * 16 * HD);

  for (int w = 0; w < 24; ++w) {
    float4 ca[2][2];
    short8 cw[8];
#pragma unroll
    for (int mt = 0; mt < 2; ++mt) { ca[mt][0] = pa[mt][0]; ca[mt][1] = pa[mt][1]; }
#pragma unroll
    for (int nt = 0; nt < 8; ++nt) cw[nt] = pw[nt];

    if (w < 23) {
      int ko = (w + 1) * 32;
#pragma unroll
      for (int mt = 0; mt < 2; ++mt) {
        pa[mt][0] = *(const float4*)(arow[mt] + ko);
        pa[mt][1] = *(const float4*)(arow[mt] + ko + 4);
      }
#pragma unroll
      for (int nt = 0; nt < 8; ++nt)
        pw[nt] = *(const short8*)(wrow + (size_t)nt * 16 * HD + ko);
    }

    short8 afr[2];
#pragma unroll
    for (int mt = 0; mt < 2; ++mt) {
      unsigned p[4];
      p[0] = pack2(ca[mt][0].x, ca[mt][0].y);
      p[1] = pack2(ca[mt][0].z, ca[mt][0].w);
      p[2] = pack2(ca[mt][1].x, ca[mt][1].y);
      p[3] = pack2(ca[mt][1].z, ca[mt][1].w);
      afr[mt] = *(short8*)p;
    }
#pragma unroll
    for (int mt = 0; mt < 2; ++mt)
#pragma unroll
      for (int nt = 0; nt < 8; ++nt)
        acc[mt][nt] = __builtin_amdgcn_mfma_f32_16x16x32_bf16(afr[mt], cw[nt], acc[mt][nt], 0, 0, 0);
  }

  // ---- epilogue: C tile -> wave-private LDS, mask+bias+l2norm, store ----
#pragma unroll
  for (int mt = 0; mt < 2; ++mt)
#pragma unroll
    for (int nt = 0; nt < 8; ++nt)
#pragma unroll
      for (int r = 0; r < 4; ++r) {
        int row = mt * 16 + lq * 4 + r;
        cep[row * 132 + nt * 16 + lm] = acc[mt][nt][r];
      }
  __syncthreads();

  int r2 = lane >> 1, hf = lane & 1;  // row-in-tile, 64-d half
  int g = tokbase + r2;
  int qq, t;
  float fm;
  if (isQ) {
    qq = g / 31; t = g - qq * 31;
    fm = (float)q_mask[qq * SQ + t + 1];
  } else {
    qq = g / 255; t = g - qq * 255;
    fm = (float)c_mask[qq * SC + t + 1];
  }

  float v[64];
  float ss = 0.f;
#pragma unroll
  for (int j = 0; j < 16; ++j) {
    float4 cv = *(const float4*)&cep[r2 * 132 + hf * 64 + j * 4];
    float4 bv = *(const float4*)&bias[hf * 64 + j * 4];
    v[4 * j + 0] = cv.x * fm + bv.x; v[4 * j + 1] = cv.y * fm + bv.y;
    v[4 * j + 2] = cv.z * fm + bv.z; v[4 * j + 3] = cv.w * fm + bv.w;
#pragma unroll
    for (int e = 0; e < 4; ++e) ss += v[4 * j + e] * v[4 * j + e];
  }
  ss += __shfl_xor(ss, 1);
  float inv = 1.f / fmaxf(sqrtf(ss), 1e-12f);

  uint4 pk4[8];
#pragma unroll
  for (int j = 0; j < 8; ++j) {
    unsigned p[4];
#pragma unroll
    for (int e = 0; e < 4; ++e)
      p[e] = pack2(v[8 * j + 2 * e] * inv, v[8 * j + 2 * e + 1] * inv);
    pk4[j] = *(uint4*)p;
  }

  if (isQ) {
    uint4* dst = (uint4*)(qcol + ((size_t)qq * 32 + t) * DD) + hf * 8;
#pragma unroll
    for (int j = 0; j < 8; ++j) dst[j] = pk4[j];
  } else {
    uint4* rowp = (uint4*)(ccol + ((size_t)qq * 256 + t) * DD);
#pragma unroll
    for (int j = 0; j < 8; ++j) {
      int kc = hf * 8 + j;
      int p = (kc & 8) | ((kc & 7) ^ (t & 7));
      rowp[p] = pk4[j];
    }
    if (t == 254) {  // duplicate into pad row 255 (row&7 = 7)
      uint4* rowp2 = rowp + 16;
#pragma unroll
      for (int j = 0; j < 8; ++j) {
        int kc = hf * 8 + j;
        int p = (kc & 8) | ((kc & 7) ^ 7);
        rowp2[p] = pk4[j];
      }
    }
  }
}

// ---------------------------------------------------------------------------
// Sim (MFMA): sim[q,c] = (sum_i max_j qcol[q,i]·ccol[c,j]) / denom[q]
// Grid (128, 4), 256 thr = 4 waves, 2 blocks/CU. 4 q per wave (16 q/block),
// 2 c-tiles looped per block. c-tile (64 KB) staged linearly via
// global_load_lds — ccol is pre-swizzled by proj, frag reads conflict-free.
// ---------------------------------------------------------------------------
__global__ __launch_bounds__(256, 2) void sim_kernel(
    const unsigned short* __restrict__ qcolP,  // [64][32][128], row 31 zero
    const unsigned short* __restrict__ ccol,   // swizzled, row 255 dup
    const int* __restrict__ qmask,
    float* __restrict__ sim) {
  __shared__ unsigned short cbuf[256 * 128];   // 64 KB
  int tid = threadIdx.x, lane = tid & 63, wv = tid >> 6;
  int lm = lane & 15, lq = lane >> 4;
  int qb = blockIdx.y * 16 + wv * 4;  // 4 q per wave
  int c0 = blockIdx.x * 2;

  // B fragments (q side): af[q2][it][kf]
  short8 af[4][2][4];
#pragma unroll
  for (int q2 = 0; q2 < 4; ++q2)
#pragma unroll
    for (int it = 0; it < 2; ++it)
#pragma unroll
      for (int kf = 0; kf < 4; ++kf)
        af[q2][it][kf] = *(const short8*)(qcolP +
            (((size_t)(qb + q2) * 32 + it * 16 + lm) * DD + kf * 32 + lq * 8));

  float dinv[4];
#pragma unroll
  for (int q2 = 0; q2 < 4; ++q2) {
    float v = (lane >= 1 && lane < 32) ? (float)qmask[(qb + q2) * SQ + lane] : 0.f;
    for (int off = 1; off < 64; off <<= 1) v += __shfl_xor(v, off);
    dinv[q2] = 1.f / v;
  }

  for (int cc = 0; cc < 2; ++cc) {
    int c = c0 + cc;
    __syncthreads();
    const unsigned short* src = ccol + (size_t)c * SC * DD;
#pragma unroll
    for (int i = 0; i < 16; ++i)
      gl_lds16(src + (size_t)(i * 256 + wv * 64 + lane) * 8,
               (char*)cbuf + (size_t)(i * 256 + wv * 64) * 16);
    __syncthreads();

    float rmax[4][2];
#pragma unroll
    for (int q2 = 0; q2 < 4; ++q2) { rmax[q2][0] = -__builtin_inff(); rmax[q2][1] = -__builtin_inff(); }

    for (int jt = 0; jt < 16; ++jt) {
      short8 cf[4];  // A operand: c rows jt*16+lm
#pragma unroll
      for (int kf = 0; kf < 4; ++kf) {
        int row = jt * 16 + lm;
        int kc = kf * 4 + lq;
        int p = (kc & 8) | ((kc & 7) ^ (row & 7));
        cf[kf] = *(const short8*)&cbuf[(size_t)(row * 16 + p) * 8];
      }
#pragma unroll
      for (int q2 = 0; q2 < 4; ++q2)
#pragma unroll
        for (int it = 0; it < 2; ++it) {
          f32x4 acc = (f32x4){0.f, 0.f, 0.f, 0.f};
#pragma unroll
          for (int kf = 0; kf < 4; ++kf)
            acc = __builtin_amdgcn_mfma_f32_16x16x32_bf16(cf[kf], af[q2][it][kf], acc, 0, 0, 0);
          float loc = fmaxf(fmaxf(acc[0], acc[1]), fmaxf(acc[2], acc[3]));
          rmax[q2][it] = fmaxf(rmax[q2][it], loc);
        }
    }

#pragma unroll
    for (int q2 = 0; q2 < 4; ++q2) {
      float m0 = rmax[q2][0], m1 = rmax[q2][1];
      m0 = fmaxf(m0, __shfl_xor(m0, 16)); m0 = fmaxf(m0, __shfl_xor(m0, 32));
      m1 = fmaxf(m1, __shfl_xor(m1, 16)); m1 = fmaxf(m1, __shfl_xor(m1, 32));
      // q-row i = lm (+16 for it=1); pad row 31 = (it=1, lm=15) excluded
      float s = m0 + ((lm == 15) ? 0.f : m1);
      s += __shfl_xor(s, 1); s += __shfl_xor(s, 2);
      s += __shfl_xor(s, 4); s += __shfl_xor(s, 8);
      if (lane == 0) sim[(qb + q2) * CN + c] = s * dinv[q2];
    }
  }
}

// ---------------------------------------------------------------------------
extern "C" void kernel_launch(void* const* d_in, const int* in_sizes, int n_in,
                              void* d_out, int out_size, void* d_ws, size_t ws_size,
                              hipStream_t stream) {
  const float* q_hidden = (const float*)d_in[0];
  const float* c_hidden = (const float*)d_in[1];
  const float* W = (const float*)d_in[2];
  const float* bias = (const float*)d_in[3];
  const int* q_mask = (const int*)d_in[4];
  const int* c_mask = (const int*)d_in[5];

  float* out = (float*)d_out;
  float* sim = out;                      // 64*256
  float* q_pooled = out + QN * CN;       // 64*768
  float* c_pooled = q_pooled + QN * HD;  // 256*768

  unsigned short* WtS   = (unsigned short*)d_ws;                        // 192 KB
  unsigned short* qcolP = (unsigned short*)((char*)d_ws + (256 << 10)); // 512 KB
  unsigned short* ccol  = (unsigned short*)((char*)d_ws + (1 << 20));   // 16 MB

  prep_kernel<<<DD + QN + CN, 256, 0, stream>>>(W, q_hidden, q_mask, c_hidden, c_mask,
                                                WtS, q_pooled, c_pooled, qcolP);
  proj_kernel<<<2102, 64, 0, stream>>>(q_hidden, c_hidden, q_mask, c_mask,
                                       WtS, bias, qcolP, ccol);
  sim_kernel<<<dim3(128, 4), 256, 0, stream>>>(qcolP, ccol, q_mask, sim);
}